// Round 10
// baseline (160.124 us; speedup 1.0000x reference)
//
#include <hip/hip_runtime.h>
#include <hip/hip_bf16.h>

// Problem constants (fixed-shape problem)
#define KNB    32
#define DEMB   128
#define HIDN   100
#define OUTU   20
#define HHEADS 5
#define OUTW   228   // H*OUT + D = 100 + 128

#define HROWS  64    // emb rows per sa_hproj block

typedef __attribute__((ext_vector_type(4))) float f32x4;
typedef __attribute__((ext_vector_type(8))) short bf16x8;

__device__ __forceinline__ unsigned short f2bf(float f) {
    union { float f; unsigned u; } v; v.f = f;
    unsigned r = (v.u + 0x7fffu + ((v.u >> 16) & 1u)) >> 16;
    return (unsigned short)r;
}
__device__ __forceinline__ unsigned pkbf(float lo, float hi) {
    unsigned r;
    asm("v_cvt_pk_bf16_f32 %0, %1, %2" : "=v"(r) : "v"(lo), "v"(hi));
    return r;
}
__device__ __forceinline__ bf16x8 cvt8(float4 a, float4 b) {
    union { unsigned u[4]; bf16x8 v; } t;
    t.u[0] = pkbf(a.x, a.y); t.u[1] = pkbf(a.z, a.w);
    t.u[2] = pkbf(b.x, b.y); t.u[3] = pkbf(b.z, b.w);
    return t.v;
}

// ---------------- prep: frag-major W1 halves + W2 ----------------
__global__ void sa_prep(const float* __restrict__ W1, const float* __restrict__ W2,
                        unsigned short* __restrict__ W1fN, unsigned short* __restrict__ W1fM,
                        unsigned short* __restrict__ W2f) {
    int idx = blockIdx.x * 256 + threadIdx.x;          // 32768 total
    if (idx < 14336) {
        int e = idx & 7, lane = (idx >> 3) & 63, ks = (idx >> 9) & 3, jt = idx >> 11;
        int j = jt * 16 + (lane & 15);
        int d = ks * 32 + (lane >> 4) * 8 + e;
        W1fN[idx] = (j < HIDN) ? f2bf(W1[d * HIDN + j]) : (unsigned short)0;
    } else if (idx < 28672) {
        int i2 = idx - 14336;
        int e = i2 & 7, lane = (i2 >> 3) & 63, ks = (i2 >> 9) & 3, jt = i2 >> 11;
        int j = jt * 16 + (lane & 15);
        int d = ks * 32 + (lane >> 4) * 8 + e;
        W1fM[i2] = (j < HIDN) ? f2bf(W1[(128 + d) * HIDN + j]) : (unsigned short)0;
    } else {
        int i2 = idx - 28672;                          // < 4096
        int e = i2 & 7, lane = (i2 >> 3) & 63, ot = (i2 >> 9) & 1, ks = i2 >> 10;
        int o = ot * 16 + (lane & 15);
        int jj = ks * 32 + (lane >> 4) * 8 + e;
        W2f[i2] = (o < OUTU && jj < HIDN) ? f2bf(W2[jj * OUTU + o]) : (unsigned short)0;
    }
}

// ---------------- hproj: streaming GEMM via coalesced LDS staging ----------------
// 64 rows/block, 4 waves (16 rows each). Stage f32 rows coalesced into XOR-swizzled LDS,
// then read B-frags conflict-free. 32 KB LDS -> 5 blocks/CU (20 waves).
__global__ __launch_bounds__(256, 5)
void sa_hproj(const float* __restrict__ emb, const unsigned short* __restrict__ W1fN,
              unsigned short* __restrict__ hproj, int ntot) {
    __shared__ char xs[HROWS * 512];     // 32 KB
    const int tid = threadIdx.x, lane = tid & 63, wid = tid >> 6;
    const int l15 = lane & 15, h4 = lane >> 4;
    const size_t rbase = (size_t)blockIdx.x * HROWS;

    // stage: 64 rows x 512 B coalesced (8 x 4KB instructions), XOR-swizzle bytes 4..6 by row
#pragma unroll
    for (int i = 0; i < 8; ++i) {
        int off = tid * 16 + i * 4096;
        int row = off >> 9, col = off & 511;
        size_t gr = rbase + row; if (gr >= (size_t)ntot) gr = (size_t)ntot - 1;
        float4 v = *(const float4*)((const char*)emb + gr * 512 + col);
        *(float4*)(xs + row * 512 + (col ^ ((row & 7) << 4))) = v;
    }
    __syncthreads();

    const int mrow = wid * 16;           // this wave's 16-row m-tile
    const bf16x8* wv = (const bf16x8*)W1fN;
    f32x4 acc[7] = {};
#pragma unroll
    for (int ks = 0; ks < 4; ++ks) {
        const int r = mrow + l15;
        const int sw = (l15 & 7) << 4;   // r&7 == l15&7 (mrow multiple of 16)
        const int cb = ks * 128 + h4 * 32;
        float4 e0 = *(const float4*)(xs + r * 512 + ((cb)      ^ sw));
        float4 e1 = *(const float4*)(xs + r * 512 + ((cb + 16) ^ sw));
        bf16x8 b = cvt8(e0, e1);
#pragma unroll
        for (int jt = 0; jt < 7; ++jt)
            acc[jt] = __builtin_amdgcn_mfma_f32_16x16x32_bf16(wv[(jt * 4 + ks) * 64 + lane], b, acc[jt], 0, 0, 0);
    }
    // store bf16 rows (cols [100,128) zero via zero weight rows / explicit zeros)
#pragma unroll
    for (int jt = 0; jt < 8; ++jt) {
        int j0 = jt * 16 + h4 * 4;
        size_t r = rbase + mrow + l15;
        if (r < (size_t)ntot) {
            uint2 v;
            if (jt < 7) v = make_uint2(pkbf(acc[jt][0], acc[jt][1]), pkbf(acc[jt][2], acc[jt][3]));
            else        v = make_uint2(0u, 0u);
            *(uint2*)((char*)hproj + r * 256 + j0 * 2) = v;
        }
    }
}

// ---------------- nproj: node-half projection + b1, f32 out ----------------
__global__ __launch_bounds__(256, 2)
void sa_nproj(const float* __restrict__ emb, const int* __restrict__ node_idx,
              const float* __restrict__ b1, const unsigned short* __restrict__ W1fM,
              float* __restrict__ nproj, int nn) {
    const int tid = threadIdx.x, lane = tid & 63, wid = tid >> 6;
    const int l15 = lane & 15, h4 = lane >> 4;
    const int n0 = blockIdx.x * 128 + wid * 32 + l15;
    const int n1 = n0 + 16;
    const int n0c = n0 < nn ? n0 : nn - 1;
    const int n1c = n1 < nn ? n1 : nn - 1;
    const float* p0 = emb + (size_t)node_idx[n0c] * DEMB + h4 * 8;
    const float* p1 = emb + (size_t)node_idx[n1c] * DEMB + h4 * 8;
    const bf16x8* wv = (const bf16x8*)W1fM;

    f32x4 acc[7][2] = {};
#pragma unroll
    for (int ks = 0; ks < 4; ++ks) {
        bf16x8 b0 = cvt8(*(const float4*)(p0 + ks * 32), *(const float4*)(p0 + ks * 32 + 4));
        bf16x8 b1v = cvt8(*(const float4*)(p1 + ks * 32), *(const float4*)(p1 + ks * 32 + 4));
#pragma unroll
        for (int jt = 0; jt < 7; ++jt) {
            bf16x8 a = wv[(jt * 4 + ks) * 64 + lane];
            acc[jt][0] = __builtin_amdgcn_mfma_f32_16x16x32_bf16(a, b0, acc[jt][0], 0, 0, 0);
            acc[jt][1] = __builtin_amdgcn_mfma_f32_16x16x32_bf16(a, b1v, acc[jt][1], 0, 0, 0);
        }
    }
#pragma unroll
    for (int jt = 0; jt < 8; ++jt) {
        int j0 = jt * 16 + h4 * 4;
        float4 bv;
        if (jt < 7 && j0 + 3 < HIDN) bv = *(const float4*)(b1 + j0);
        else bv = make_float4(0.f, 0.f, 0.f, 0.f);
#pragma unroll
        for (int mt = 0; mt < 2; ++mt) {
            int n = mt ? n1 : n0;
            if (n < nn) {
                float4 v;
                if (jt < 7) {
                    f32x4 a = acc[jt][mt];
                    v = make_float4(a[0] + bv.x, a[1] + bv.y, a[2] + bv.z, a[3] + bv.w);
                } else v = make_float4(0.f, 0.f, 0.f, 0.f);
                *(float4*)(nproj + (size_t)n * 128 + j0) = v;
            }
        }
    }
}

// hid A-frag: relu(bf16(hproj) + f32(nproj)) -> packed bf16x8
__device__ __forceinline__ bf16x8 mkhid(uint4 hp, float4 na, float4 nb) {
    union { unsigned u[4]; bf16x8 v; } t;
    union { unsigned u; float f; } c0, c1;
    c0.u = hp.x << 16;          c1.u = hp.x & 0xffff0000u;
    t.u[0] = pkbf(fmaxf(c0.f + na.x, 0.f), fmaxf(c1.f + na.y, 0.f));
    c0.u = hp.y << 16;          c1.u = hp.y & 0xffff0000u;
    t.u[1] = pkbf(fmaxf(c0.f + na.z, 0.f), fmaxf(c1.f + na.w, 0.f));
    c0.u = hp.z << 16;          c1.u = hp.z & 0xffff0000u;
    t.u[2] = pkbf(fmaxf(c0.f + nb.x, 0.f), fmaxf(c1.f + nb.y, 0.f));
    c0.u = hp.w << 16;          c1.u = hp.w & 0xffff0000u;
    t.u[3] = pkbf(fmaxf(c0.f + nb.z, 0.f), fmaxf(c1.f + nb.w, 0.f));
    return t.v;
}

// ---------------- main: 1 node/wave, grid 5000 blocks -> ~24 waves/CU of gather MLP ----------------
__global__ __launch_bounds__(256, 6)
void sa_main(const float* __restrict__ emb,
             const int* __restrict__ node_idx,
             const int* __restrict__ neigh_idx,
             const float* __restrict__ b2,
             const float* __restrict__ Wa,
             const float* __restrict__ ba,
             const unsigned short* __restrict__ hproj,
             const float* __restrict__ nproj,
             const unsigned short* __restrict__ W2f,
             float* __restrict__ out, int nnodes) {
    __shared__ char smem[4 * 3520];
    const int tid = threadIdx.x, lane = tid & 63, wid = tid >> 6;
    const int l15 = lane & 15, h4 = lane >> 4;

    char* wbase = smem + wid * 3520;
    float* tT_s = (float*)wbase;              // 20*36*4 = 2880 B
    float* pf_s = (float*)(wbase + 2880);     // 160*4   = 640 B

    const int node = blockIdx.x * 4 + wid;    // 5000 x 4 = 20000 exact
    if (node >= nnodes) return;
    const int* nip = neigh_idx + (size_t)node * KNB;
    const int m0 = nip[l15], m1 = nip[16 + l15];
    const int nid = node_idx[node];

    // ---- issue all gathers ----
    const char* hp0 = (const char*)hproj + (size_t)m0 * 256 + h4 * 16;
    const char* hp1 = (const char*)hproj + (size_t)m1 * 256 + h4 * 16;
    const float* np = nproj + (size_t)node * 128 + h4 * 8;
    uint4 g0[4], g1[4]; float4 na[4], nb4[4];
#pragma unroll
    for (int ks = 0; ks < 4; ++ks) {
        g0[ks]  = *(const uint4*)(hp0 + ks * 64);
        g1[ks]  = *(const uint4*)(hp1 + ks * 64);
        na[ks]  = *(const float4*)(np + ks * 32);
        nb4[ks] = *(const float4*)(np + ks * 32 + 4);
    }
    float4 ncp;
    if (lane < 32) ncp = ((const float4*)(emb + (size_t)nid * DEMB))[lane];

    // W2 fragments (coalesced, L1/L2-hot)
    bf16x8 w2r[4][2];
#pragma unroll
    for (int ks = 0; ks < 4; ++ks)
#pragma unroll
        for (int ot = 0; ot < 2; ++ot)
            w2r[ks][ot] = ((const bf16x8*)W2f)[(ks * 2 + ot) * 64 + lane];

    __builtin_amdgcn_sched_barrier(0);

    if (lane < 32)
        ((float4*)(out + (size_t)node * OUTW + HHEADS * OUTU))[lane] = ncp;

    // ---- GEMM2: hid built in-register from hproj+nproj ----
    f32x4 acc[2][2] = {};
#pragma unroll
    for (int ks = 0; ks < 4; ++ks) {
        bf16x8 a0 = mkhid(g0[ks], na[ks], nb4[ks]);
        bf16x8 a1 = mkhid(g1[ks], na[ks], nb4[ks]);
        acc[0][0] = __builtin_amdgcn_mfma_f32_16x16x32_bf16(a0, w2r[ks][0], acc[0][0], 0, 0, 0);
        acc[0][1] = __builtin_amdgcn_mfma_f32_16x16x32_bf16(a0, w2r[ks][1], acc[0][1], 0, 0, 0);
        acc[1][0] = __builtin_amdgcn_mfma_f32_16x16x32_bf16(a1, w2r[ks][0], acc[1][0], 0, 0, 0);
        acc[1][1] = __builtin_amdgcn_mfma_f32_16x16x32_bf16(a1, w2r[ks][1], acc[1][1], 0, 0, 0);
    }

    // ---- t = relu(D2 + b2), store transposed tT[o][m] ----
#pragma unroll
    for (int ot = 0; ot < 2; ++ot) {
        int o = ot * 16 + l15;
        if (o < OUTU) {
            float b2v = b2[o];
#pragma unroll
            for (int mt = 0; mt < 2; ++mt) {
                int mm0 = mt * 16 + h4 * 4;
                f32x4 a = acc[mt][ot];
                *(float4*)&tT_s[o * 36 + mm0] =
                    make_float4(fmaxf(a[0] + b2v, 0.f), fmaxf(a[1] + b2v, 0.f),
                                fmaxf(a[2] + b2v, 0.f), fmaxf(a[3] + b2v, 0.f));
            }
        }
    }

    // ---- attention + softmax over heads ----
    {
        int mm = lane & 31;
        float tv[20];
#pragma unroll
        for (int o = 0; o < OUTU; ++o) tv[o] = tT_s[o * 36 + mm];
        float att[5];
#pragma unroll
        for (int h = 0; h < HHEADS; ++h) {
            float s = ba[h];
#pragma unroll
            for (int o = 0; o < OUTU; ++o) s += tv[o] * Wa[o * HHEADS + h];
            att[h] = fmaxf(s, 0.f);
        }
        float mx = att[0];
#pragma unroll
        for (int h = 1; h < HHEADS; ++h) mx = fmaxf(mx, att[h]);
        float e[5], sum = 0.f;
#pragma unroll
        for (int h = 0; h < HHEADS; ++h) { e[h] = __expf(att[h] - mx); sum += e[h]; }
        float inv = 1.f / sum;
        if (lane < 32) {
#pragma unroll
            for (int h = 0; h < HHEADS; ++h) pf_s[mm * HHEADS + h] = e[h] * inv;
        }
    }

    // ---- aggregate: out[n, h*20+o] = sum_k pf[h*32+k] * t[k][o]  (reshape-faithful) ----
#pragma unroll
    for (int pass = 0; pass < 2; ++pass) {
        int idx = pass * 64 + lane;
        if (idx < HHEADS * OUTU) {
            int h = idx / OUTU, o = idx % OUTU;
            float s = 0.f;
#pragma unroll
            for (int kk = 0; kk < 8; ++kk) {
                float4 p4 = *(const float4*)&pf_s[h * 32 + kk * 4];
                float4 t4 = *(const float4*)&tT_s[o * 36 + kk * 4];
                s += p4.x * t4.x + p4.y * t4.y + p4.z * t4.z + p4.w * t4.w;
            }
            out[(size_t)node * OUTW + idx] = s;
        }
    }
}

extern "C" void kernel_launch(void* const* d_in, const int* in_sizes, int n_in,
                              void* d_out, int out_size, void* d_ws, size_t ws_size,
                              hipStream_t stream) {
    const float* emb      = (const float*)d_in[0];
    const int*   node_idx = (const int*)d_in[1];
    const int*   neigh_idx= (const int*)d_in[2];
    const float* W1       = (const float*)d_in[3];
    const float* b1       = (const float*)d_in[4];
    const float* W2       = (const float*)d_in[5];
    const float* b2       = (const float*)d_in[6];
    const float* Wa       = (const float*)d_in[7];
    const float* ba       = (const float*)d_in[8];
    float* out = (float*)d_out;

    int ntot = in_sizes[0] / DEMB;                          // 200000
    int n    = in_sizes[1];                                 // 20000

    // ws layout
    unsigned short* W1fN = (unsigned short*)d_ws;                        // 28672 B
    unsigned short* W1fM = W1fN + 14336;                                 // 28672 B
    unsigned short* W2f  = W1fM + 14336;                                 //  8192 B
    unsigned short* hproj = (unsigned short*)((char*)d_ws + 65536);      // ntot*128*2
    float* nproj = (float*)((char*)d_ws + 65536 + (size_t)ntot * 256);   // n*128*4

    sa_prep<<<128, 256, 0, stream>>>(W1, W2, W1fN, W1fM, W2f);
    sa_hproj<<<(ntot + HROWS - 1) / HROWS, 256, 0, stream>>>(emb, W1fN, hproj, ntot);
    sa_nproj<<<(n + 127) / 128, 256, 0, stream>>>(emb, node_idx, b1, W1fM, nproj, n);
    sa_main<<<(n + 3) / 4, 256, 0, stream>>>(
        emb, node_idx, neigh_idx, b2, Wa, ba, hproj, nproj, W2f, out, n);
}

// Round 11
// 93.601 us; speedup vs baseline: 1.7107x; 1.7107x over previous
//
#include <hip/hip_runtime.h>
#include <hip/hip_bf16.h>

// Problem constants (fixed-shape problem)
#define KNB    32
#define DEMB   128
#define HIDN   100
#define OUTU   20
#define HHEADS 5
#define OUTW   228   // H*OUT + D = 100 + 128

#define HROWS  64    // emb rows per sa_hproj block

typedef __attribute__((ext_vector_type(4))) float f32x4;
typedef __attribute__((ext_vector_type(8))) short bf16x8;

__device__ __forceinline__ unsigned short f2bf(float f) {
    union { float f; unsigned u; } v; v.f = f;
    unsigned r = (v.u + 0x7fffu + ((v.u >> 16) & 1u)) >> 16;
    return (unsigned short)r;
}
__device__ __forceinline__ unsigned pkbf(float lo, float hi) {
    unsigned r;
    asm("v_cvt_pk_bf16_f32 %0, %1, %2" : "=v"(r) : "v"(lo), "v"(hi));
    return r;
}
__device__ __forceinline__ bf16x8 cvt8(float4 a, float4 b) {
    union { unsigned u[4]; bf16x8 v; } t;
    t.u[0] = pkbf(a.x, a.y); t.u[1] = pkbf(a.z, a.w);
    t.u[2] = pkbf(b.x, b.y); t.u[3] = pkbf(b.z, b.w);
    return t.v;
}

// ---------------- prep: frag-major W1 halves + W2 ----------------
__global__ void sa_prep(const float* __restrict__ W1, const float* __restrict__ W2,
                        unsigned short* __restrict__ W1fN, unsigned short* __restrict__ W1fM,
                        unsigned short* __restrict__ W2f) {
    int idx = blockIdx.x * 256 + threadIdx.x;          // 32768 total
    if (idx < 14336) {
        int e = idx & 7, lane = (idx >> 3) & 63, ks = (idx >> 9) & 3, jt = idx >> 11;
        int j = jt * 16 + (lane & 15);
        int d = ks * 32 + (lane >> 4) * 8 + e;
        W1fN[idx] = (j < HIDN) ? f2bf(W1[d * HIDN + j]) : (unsigned short)0;
    } else if (idx < 28672) {
        int i2 = idx - 14336;
        int e = i2 & 7, lane = (i2 >> 3) & 63, ks = (i2 >> 9) & 3, jt = i2 >> 11;
        int j = jt * 16 + (lane & 15);
        int d = ks * 32 + (lane >> 4) * 8 + e;
        W1fM[i2] = (j < HIDN) ? f2bf(W1[(128 + d) * HIDN + j]) : (unsigned short)0;
    } else {
        int i2 = idx - 28672;                          // < 4096
        int e = i2 & 7, lane = (i2 >> 3) & 63, ot = (i2 >> 9) & 1, ks = i2 >> 10;
        int o = ot * 16 + (lane & 15);
        int jj = ks * 32 + (lane >> 4) * 8 + e;
        W2f[i2] = (o < OUTU && jj < HIDN) ? f2bf(W2[jj * OUTU + o]) : (unsigned short)0;
    }
}

// ---------------- hproj: streaming GEMM via coalesced LDS staging ----------------
// 64 rows/block, 4 waves (16 rows each). Stage f32 rows coalesced into XOR-swizzled LDS,
// then read B-frags conflict-free. 32 KB LDS -> 5 blocks/CU (20 waves).
__global__ __launch_bounds__(256, 5)
void sa_hproj(const float* __restrict__ emb, const unsigned short* __restrict__ W1fN,
              unsigned short* __restrict__ hproj, int ntot) {
    __shared__ char xs[HROWS * 512];     // 32 KB
    const int tid = threadIdx.x, lane = tid & 63, wid = tid >> 6;
    const int l15 = lane & 15, h4 = lane >> 4;
    const size_t rbase = (size_t)blockIdx.x * HROWS;

    // stage: 64 rows x 512 B coalesced (8 x 4KB instructions), XOR-swizzle bytes 4..6 by row
#pragma unroll
    for (int i = 0; i < 8; ++i) {
        int off = tid * 16 + i * 4096;
        int row = off >> 9, col = off & 511;
        size_t gr = rbase + row; if (gr >= (size_t)ntot) gr = (size_t)ntot - 1;
        float4 v = *(const float4*)((const char*)emb + gr * 512 + col);
        *(float4*)(xs + row * 512 + (col ^ ((row & 7) << 4))) = v;
    }
    __syncthreads();

    const int mrow = wid * 16;           // this wave's 16-row m-tile
    const bf16x8* wv = (const bf16x8*)W1fN;
    f32x4 acc[7] = {};
#pragma unroll
    for (int ks = 0; ks < 4; ++ks) {
        const int r = mrow + l15;
        const int sw = (l15 & 7) << 4;   // r&7 == l15&7 (mrow multiple of 16)
        const int cb = ks * 128 + h4 * 32;
        float4 e0 = *(const float4*)(xs + r * 512 + ((cb)      ^ sw));
        float4 e1 = *(const float4*)(xs + r * 512 + ((cb + 16) ^ sw));
        bf16x8 b = cvt8(e0, e1);
#pragma unroll
        for (int jt = 0; jt < 7; ++jt)
            acc[jt] = __builtin_amdgcn_mfma_f32_16x16x32_bf16(wv[(jt * 4 + ks) * 64 + lane], b, acc[jt], 0, 0, 0);
    }
    // store bf16 rows (cols [100,128) zero via zero weight rows / explicit zeros)
#pragma unroll
    for (int jt = 0; jt < 8; ++jt) {
        int j0 = jt * 16 + h4 * 4;
        size_t r = rbase + mrow + l15;
        if (r < (size_t)ntot) {
            uint2 v;
            if (jt < 7) v = make_uint2(pkbf(acc[jt][0], acc[jt][1]), pkbf(acc[jt][2], acc[jt][3]));
            else        v = make_uint2(0u, 0u);
            *(uint2*)((char*)hproj + r * 256 + j0 * 2) = v;
        }
    }
}

// ---------------- nproj: node-half projection + b1, f32 out ----------------
__global__ __launch_bounds__(256, 2)
void sa_nproj(const float* __restrict__ emb, const int* __restrict__ node_idx,
              const float* __restrict__ b1, const unsigned short* __restrict__ W1fM,
              float* __restrict__ nproj, int nn) {
    const int tid = threadIdx.x, lane = tid & 63, wid = tid >> 6;
    const int l15 = lane & 15, h4 = lane >> 4;
    const int n0 = blockIdx.x * 128 + wid * 32 + l15;
    const int n1 = n0 + 16;
    const int n0c = n0 < nn ? n0 : nn - 1;
    const int n1c = n1 < nn ? n1 : nn - 1;
    const float* p0 = emb + (size_t)node_idx[n0c] * DEMB + h4 * 8;
    const float* p1 = emb + (size_t)node_idx[n1c] * DEMB + h4 * 8;
    const bf16x8* wv = (const bf16x8*)W1fM;

    f32x4 acc[7][2] = {};
#pragma unroll
    for (int ks = 0; ks < 4; ++ks) {
        bf16x8 b0 = cvt8(*(const float4*)(p0 + ks * 32), *(const float4*)(p0 + ks * 32 + 4));
        bf16x8 b1v = cvt8(*(const float4*)(p1 + ks * 32), *(const float4*)(p1 + ks * 32 + 4));
#pragma unroll
        for (int jt = 0; jt < 7; ++jt) {
            bf16x8 a = wv[(jt * 4 + ks) * 64 + lane];
            acc[jt][0] = __builtin_amdgcn_mfma_f32_16x16x32_bf16(a, b0, acc[jt][0], 0, 0, 0);
            acc[jt][1] = __builtin_amdgcn_mfma_f32_16x16x32_bf16(a, b1v, acc[jt][1], 0, 0, 0);
        }
    }
#pragma unroll
    for (int jt = 0; jt < 8; ++jt) {
        int j0 = jt * 16 + h4 * 4;
        float4 bv;
        if (jt < 7 && j0 + 3 < HIDN) bv = *(const float4*)(b1 + j0);
        else bv = make_float4(0.f, 0.f, 0.f, 0.f);
#pragma unroll
        for (int mt = 0; mt < 2; ++mt) {
            int n = mt ? n1 : n0;
            if (n < nn) {
                float4 v;
                if (jt < 7) {
                    f32x4 a = acc[jt][mt];
                    v = make_float4(a[0] + bv.x, a[1] + bv.y, a[2] + bv.z, a[3] + bv.w);
                } else v = make_float4(0.f, 0.f, 0.f, 0.f);
                *(float4*)(nproj + (size_t)n * 128 + j0) = v;
            }
        }
    }
}

// hid A-frag: relu(bf16(hproj) + f32(nproj)) -> packed bf16x8
__device__ __forceinline__ bf16x8 mkhid(uint4 hp, float4 na, float4 nb) {
    union { unsigned u[4]; bf16x8 v; } t;
    union { unsigned u; float f; } c0, c1;
    c0.u = hp.x << 16;          c1.u = hp.x & 0xffff0000u;
    t.u[0] = pkbf(fmaxf(c0.f + na.x, 0.f), fmaxf(c1.f + na.y, 0.f));
    c0.u = hp.y << 16;          c1.u = hp.y & 0xffff0000u;
    t.u[1] = pkbf(fmaxf(c0.f + na.z, 0.f), fmaxf(c1.f + na.w, 0.f));
    c0.u = hp.z << 16;          c1.u = hp.z & 0xffff0000u;
    t.u[2] = pkbf(fmaxf(c0.f + nb.x, 0.f), fmaxf(c1.f + nb.y, 0.f));
    c0.u = hp.w << 16;          c1.u = hp.w & 0xffff0000u;
    t.u[3] = pkbf(fmaxf(c0.f + nb.z, 0.f), fmaxf(c1.f + nb.w, 0.f));
    return t.v;
}

// ---------------- main: 1 node/wave, grid 5000; launch_bounds(256,4) -> 128 VGPR, NO spill ----------------
__global__ __launch_bounds__(256, 4)
void sa_main(const float* __restrict__ emb,
             const int* __restrict__ node_idx,
             const int* __restrict__ neigh_idx,
             const float* __restrict__ b2,
             const float* __restrict__ Wa,
             const float* __restrict__ ba,
             const unsigned short* __restrict__ hproj,
             const float* __restrict__ nproj,
             const unsigned short* __restrict__ W2f,
             float* __restrict__ out, int nnodes) {
    __shared__ char smem[4 * 3520];
    const int tid = threadIdx.x, lane = tid & 63, wid = tid >> 6;
    const int l15 = lane & 15, h4 = lane >> 4;

    char* wbase = smem + wid * 3520;
    float* tT_s = (float*)wbase;              // 20*36*4 = 2880 B
    float* pf_s = (float*)(wbase + 2880);     // 160*4   = 640 B

    const int node = blockIdx.x * 4 + wid;    // 5000 x 4 = 20000 exact
    if (node >= nnodes) return;
    const int* nip = neigh_idx + (size_t)node * KNB;
    const int m0 = nip[l15], m1 = nip[16 + l15];
    const int nid = node_idx[node];

    // ---- issue all gathers ----
    const char* hp0 = (const char*)hproj + (size_t)m0 * 256 + h4 * 16;
    const char* hp1 = (const char*)hproj + (size_t)m1 * 256 + h4 * 16;
    const float* np = nproj + (size_t)node * 128 + h4 * 8;
    uint4 g0[4], g1[4]; float4 na[4], nb4[4];
#pragma unroll
    for (int ks = 0; ks < 4; ++ks) {
        g0[ks]  = *(const uint4*)(hp0 + ks * 64);
        g1[ks]  = *(const uint4*)(hp1 + ks * 64);
        na[ks]  = *(const float4*)(np + ks * 32);
        nb4[ks] = *(const float4*)(np + ks * 32 + 4);
    }
    float4 ncp;
    if (lane < 32) ncp = ((const float4*)(emb + (size_t)nid * DEMB))[lane];

    // W2 fragments (coalesced, L1/L2-hot)
    bf16x8 w2r[4][2];
#pragma unroll
    for (int ks = 0; ks < 4; ++ks)
#pragma unroll
        for (int ot = 0; ot < 2; ++ot)
            w2r[ks][ot] = ((const bf16x8*)W2f)[(ks * 2 + ot) * 64 + lane];

    __builtin_amdgcn_sched_barrier(0);

    if (lane < 32)
        ((float4*)(out + (size_t)node * OUTW + HHEADS * OUTU))[lane] = ncp;

    // ---- GEMM2: hid built in-register from hproj+nproj ----
    f32x4 acc[2][2] = {};
#pragma unroll
    for (int ks = 0; ks < 4; ++ks) {
        bf16x8 a0 = mkhid(g0[ks], na[ks], nb4[ks]);
        bf16x8 a1 = mkhid(g1[ks], na[ks], nb4[ks]);
        acc[0][0] = __builtin_amdgcn_mfma_f32_16x16x32_bf16(a0, w2r[ks][0], acc[0][0], 0, 0, 0);
        acc[0][1] = __builtin_amdgcn_mfma_f32_16x16x32_bf16(a0, w2r[ks][1], acc[0][1], 0, 0, 0);
        acc[1][0] = __builtin_amdgcn_mfma_f32_16x16x32_bf16(a1, w2r[ks][0], acc[1][0], 0, 0, 0);
        acc[1][1] = __builtin_amdgcn_mfma_f32_16x16x32_bf16(a1, w2r[ks][1], acc[1][1], 0, 0, 0);
    }

    // ---- t = relu(D2 + b2), store transposed tT[o][m] ----
#pragma unroll
    for (int ot = 0; ot < 2; ++ot) {
        int o = ot * 16 + l15;
        if (o < OUTU) {
            float b2v = b2[o];
#pragma unroll
            for (int mt = 0; mt < 2; ++mt) {
                int mm0 = mt * 16 + h4 * 4;
                f32x4 a = acc[mt][ot];
                *(float4*)&tT_s[o * 36 + mm0] =
                    make_float4(fmaxf(a[0] + b2v, 0.f), fmaxf(a[1] + b2v, 0.f),
                                fmaxf(a[2] + b2v, 0.f), fmaxf(a[3] + b2v, 0.f));
            }
        }
    }

    // ---- attention + softmax over heads ----
    {
        int mm = lane & 31;
        float tv[20];
#pragma unroll
        for (int o = 0; o < OUTU; ++o) tv[o] = tT_s[o * 36 + mm];
        float att[5];
#pragma unroll
        for (int h = 0; h < HHEADS; ++h) {
            float s = ba[h];
#pragma unroll
            for (int o = 0; o < OUTU; ++o) s += tv[o] * Wa[o * HHEADS + h];
            att[h] = fmaxf(s, 0.f);
        }
        float mx = att[0];
#pragma unroll
        for (int h = 1; h < HHEADS; ++h) mx = fmaxf(mx, att[h]);
        float e[5], sum = 0.f;
#pragma unroll
        for (int h = 0; h < HHEADS; ++h) { e[h] = __expf(att[h] - mx); sum += e[h]; }
        float inv = 1.f / sum;
        if (lane < 32) {
#pragma unroll
            for (int h = 0; h < HHEADS; ++h) pf_s[mm * HHEADS + h] = e[h] * inv;
        }
    }

    // ---- aggregate: out[n, h*20+o] = sum_k pf[h*32+k] * t[k][o]  (reshape-faithful) ----
#pragma unroll
    for (int pass = 0; pass < 2; ++pass) {
        int idx = pass * 64 + lane;
        if (idx < HHEADS * OUTU) {
            int h = idx / OUTU, o = idx % OUTU;
            float s = 0.f;
#pragma unroll
            for (int kk = 0; kk < 8; ++kk) {
                float4 p4 = *(const float4*)&pf_s[h * 32 + kk * 4];
                float4 t4 = *(const float4*)&tT_s[o * 36 + kk * 4];
                s += p4.x * t4.x + p4.y * t4.y + p4.z * t4.z + p4.w * t4.w;
            }
            out[(size_t)node * OUTW + idx] = s;
        }
    }
}

extern "C" void kernel_launch(void* const* d_in, const int* in_sizes, int n_in,
                              void* d_out, int out_size, void* d_ws, size_t ws_size,
                              hipStream_t stream) {
    const float* emb      = (const float*)d_in[0];
    const int*   node_idx = (const int*)d_in[1];
    const int*   neigh_idx= (const int*)d_in[2];
    const float* W1       = (const float*)d_in[3];
    const float* b1       = (const float*)d_in[4];
    const float* W2       = (const float*)d_in[5];
    const float* b2       = (const float*)d_in[6];
    const float* Wa       = (const float*)d_in[7];
    const float* ba       = (const float*)d_in[8];
    float* out = (float*)d_out;

    int ntot = in_sizes[0] / DEMB;                          // 200000
    int n    = in_sizes[1];                                 // 20000

    // ws layout
    unsigned short* W1fN = (unsigned short*)d_ws;                        // 28672 B
    unsigned short* W1fM = W1fN + 14336;                                 // 28672 B
    unsigned short* W2f  = W1fM + 14336;                                 //  8192 B
    unsigned short* hproj = (unsigned short*)((char*)d_ws + 65536);      // ntot*128*2
    float* nproj = (float*)((char*)d_ws + 65536 + (size_t)ntot * 256);   // n*128*4

    sa_prep<<<128, 256, 0, stream>>>(W1, W2, W1fN, W1fM, W2f);
    sa_hproj<<<(ntot + HROWS - 1) / HROWS, 256, 0, stream>>>(emb, W1fN, hproj, ntot);
    sa_nproj<<<(n + 127) / 128, 256, 0, stream>>>(emb, node_idx, b1, W1fM, nproj, n);
    sa_main<<<(n + 3) / 4, 256, 0, stream>>>(
        emb, node_idx, neigh_idx, b2, Wa, ba, hproj, nproj, W2f, out, n);
}